// Round 1
// baseline (352.408 us; speedup 1.0000x reference)
//
#include <hip/hip_runtime.h>
#include <cstdint>

using u16    = unsigned short;
using u32    = unsigned int;
using bf16x8 = __attribute__((ext_vector_type(8))) __bf16;
using f32x4  = __attribute__((ext_vector_type(4))) float;

// Problem constants
#define E_    512
#define DH_   64
#define H_    8
#define B_    4
#define NX_   1024
#define NY_   1024
#define FF_   2048
#define M_    4096   // B*NX = B*NY

__device__ __forceinline__ u16 f2bf(float f) {
    u32 u = __builtin_bit_cast(u32, f);
    u += 0x7FFFu + ((u >> 16) & 1u);
    return (u16)(u >> 16);
}

// ---------------- f32 -> bf16 convert ----------------
__global__ __launch_bounds__(256) void cvt_kernel(const float* __restrict__ in,
                                                  u16* __restrict__ out, int n)
{
    int i = (blockIdx.x * 256 + threadIdx.x) * 4;
    if (i >= n) return;
    float4 v = *(const float4*)(in + i);
    uint2 o;
    o.x = (u32)f2bf(v.x) | ((u32)f2bf(v.y) << 16);
    o.y = (u32)f2bf(v.z) | ((u32)f2bf(v.w) << 16);
    *(uint2*)(out + i) = o;
}

// ---------------- weight transpose + convert: src (K,N) f32 -> dst (N,K) bf16 ----------------
__global__ __launch_bounds__(256) void wtrans_kernel(const float* __restrict__ Wq,
                                                     const float* __restrict__ Wk,
                                                     const float* __restrict__ Wv,
                                                     const float* __restrict__ Wo,
                                                     const float* __restrict__ W1,
                                                     const float* __restrict__ W2,
                                                     u16* __restrict__ wt)
{
    int z = blockIdx.z;
    const float* src = nullptr; u16* dst = nullptr; int K = 512, N = 512;
    switch (z) {
        case 0: case 1: case 2: case 3:
            src = Wq + (size_t)z * 262144;        dst = wt + (size_t)z * 262144;            break;
        case 4: case 5: case 6: case 7:
            src = Wk + (size_t)(z - 4) * 262144;  dst = wt + 1048576 + (size_t)(z - 4) * 262144; break;
        case 8:  src = Wv + 3 * 262144;  dst = wt + 2097152; break;
        case 9:  src = Wo + 3 * 262144;  dst = wt + 2359296; break;
        case 10: src = W1 + 3 * 1048576; dst = wt + 2621440; K = 512;  N = 2048; break;
        default: src = W2 + 3 * 1048576; dst = wt + 3670016; K = 2048; N = 512;  break;
    }
    int n0 = blockIdx.x * 32, k0 = blockIdx.y * 32;
    if (n0 >= N || k0 >= K) return;
    __shared__ float tile[32][33];
    int tx = threadIdx.x, ty = threadIdx.y;
    #pragma unroll
    for (int i = 0; i < 4; i++) {
        int r = ty + i * 8;
        tile[r][tx] = src[(size_t)(k0 + r) * N + n0 + tx];
    }
    __syncthreads();
    #pragma unroll
    for (int i = 0; i < 4; i++) {
        int rn = ty + i * 8;
        dst[(size_t)(n0 + rn) * K + k0 + tx] = f2bf(tile[tx][rn]);
    }
}

// ---------------- shared GEMM core: C(128x128) = A(M,K) @ BT(N,K)^T, bf16 in, f32 acc ----------------
__device__ __forceinline__ void gemm_core(const u16* __restrict__ A,
                                          const u16* __restrict__ BT,
                                          int K, int m0, int n0,
                                          u16 As[][40], u16 Bs[][40],
                                          f32x4 acc[4][4])
{
    const int t    = threadIdx.x;
    const int lane = t & 63, wid = t >> 6;
    const int wm = wid >> 1, wn = wid & 1;
    const int lrow = lane & 15, kg = lane >> 4;
    for (int ks = 0; ks < K; ks += 32) {
        #pragma unroll
        for (int i = 0; i < 2; i++) {
            int idx = t + i * 256;                // 0..511
            int r = idx >> 2, q = idx & 3;
            *(uint4*)&As[r][q * 8] = *(const uint4*)&A[(size_t)(m0 + r) * K + ks + q * 8];
            *(uint4*)&Bs[r][q * 8] = *(const uint4*)&BT[(size_t)(n0 + r) * K + ks + q * 8];
        }
        __syncthreads();
        bf16x8 af[4], bfv[4];
        #pragma unroll
        for (int i = 0; i < 4; i++) af[i]  = *(const bf16x8*)&As[wm * 64 + i * 16 + lrow][kg * 8];
        #pragma unroll
        for (int j = 0; j < 4; j++) bfv[j] = *(const bf16x8*)&Bs[wn * 64 + j * 16 + lrow][kg * 8];
        #pragma unroll
        for (int i = 0; i < 4; i++)
            #pragma unroll
            for (int j = 0; j < 4; j++)
                acc[i][j] = __builtin_amdgcn_mfma_f32_16x16x32_bf16(af[i], bfv[j], acc[i][j], 0, 0, 0);
        __syncthreads();
    }
}

// ---------------- batched QKV projection GEMM (z: 0-3 Q_l, 4-7 K_l, 8 V_3) ----------------
__global__ __launch_bounds__(256) void qkv_gemm_kernel(const u16* __restrict__ x16,
                                                       const u16* __restrict__ y16,
                                                       const u16* __restrict__ wt,
                                                       u16* __restrict__ qkv,
                                                       const float* __restrict__ bq,
                                                       const float* __restrict__ bk,
                                                       const float* __restrict__ bv)
{
    __shared__ u16 As[128][40];
    __shared__ u16 Bs[128][40];
    const int z = blockIdx.z;
    const u16* A; const u16* BT; const float* bias;
    if (z < 4)      { A = x16; BT = wt + (size_t)z * 262144;                 bias = bq + z * 512; }
    else if (z < 8) { A = y16; BT = wt + 1048576 + (size_t)(z - 4) * 262144; bias = bk + (z - 4) * 512; }
    else            { A = y16; BT = wt + 2097152;                            bias = bv + 3 * 512; }
    u16* out = qkv + (size_t)z * 2097152;

    const int m0 = blockIdx.y * 128, n0 = blockIdx.x * 128;
    f32x4 acc[4][4];
    #pragma unroll
    for (int i = 0; i < 4; i++)
        #pragma unroll
        for (int j = 0; j < 4; j++) acc[i][j] = f32x4{0.f, 0.f, 0.f, 0.f};
    gemm_core(A, BT, 512, m0, n0, As, Bs, acc);

    const int lane = threadIdx.x & 63, wid = threadIdx.x >> 6;
    const int wm = wid >> 1, wn = wid & 1;
    const int lrow = lane & 15, kg = lane >> 4;
    #pragma unroll
    for (int i = 0; i < 4; i++)
        #pragma unroll
        for (int j = 0; j < 4; j++)
            #pragma unroll
            for (int r = 0; r < 4; r++) {
                int row = m0 + wm * 64 + i * 16 + kg * 4 + r;
                int col = n0 + wn * 64 + j * 16 + lrow;
                out[(size_t)row * 512 + col] = f2bf(acc[i][j][r] + bias[col]);
            }
}

// ---------------- generic GEMM with epilogue. EPI: 1 = f32 out + bias + residual, 2 = bf16 out + bias + exact GELU ----------------
template<int EPI>
__global__ __launch_bounds__(256) void gemm_bt_kernel(const u16* __restrict__ A,
                                                      const u16* __restrict__ BT,
                                                      const float* __restrict__ bias,
                                                      void* __restrict__ outp,
                                                      const float* __restrict__ res,
                                                      int N, int K)
{
    __shared__ u16 As[128][40];
    __shared__ u16 Bs[128][40];
    const int m0 = blockIdx.y * 128, n0 = blockIdx.x * 128;
    f32x4 acc[4][4];
    #pragma unroll
    for (int i = 0; i < 4; i++)
        #pragma unroll
        for (int j = 0; j < 4; j++) acc[i][j] = f32x4{0.f, 0.f, 0.f, 0.f};
    gemm_core(A, BT, K, m0, n0, As, Bs, acc);

    const int lane = threadIdx.x & 63, wid = threadIdx.x >> 6;
    const int wm = wid >> 1, wn = wid & 1;
    const int lrow = lane & 15, kg = lane >> 4;
    #pragma unroll
    for (int i = 0; i < 4; i++)
        #pragma unroll
        for (int j = 0; j < 4; j++)
            #pragma unroll
            for (int r = 0; r < 4; r++) {
                int row = m0 + wm * 64 + i * 16 + kg * 4 + r;
                int col = n0 + wn * 64 + j * 16 + lrow;
                float v = acc[i][j][r] + bias[col];
                if constexpr (EPI == 1) {
                    ((float*)outp)[(size_t)row * N + col] = v + res[(size_t)row * N + col];
                } else {
                    v = 0.5f * v * (1.f + erff(v * 0.70710678118654752f));
                    ((u16*)outp)[(size_t)row * N + col] = f2bf(v);
                }
            }
}

// ---------------- V transpose per head: v (b,h,m,d) -> vt (b,h,d,m) ----------------
__global__ __launch_bounds__(256) void vtrans_kernel(const u16* __restrict__ v, u16* __restrict__ vt)
{
    const int bh = blockIdx.y, m0 = blockIdx.x * 64;
    const int b = bh >> 3, h = bh & 7;
    const u16* src = v + (size_t)b * 524288 + (size_t)h * 65536;   // (1024 m, 64 d)
    u16* dst = vt + (size_t)bh * 65536;                            // (64 d, 1024 m)
    __shared__ u16 tile[64][72];
    const int t = threadIdx.x;
    #pragma unroll
    for (int i = 0; i < 2; i++) {
        int idx = t + i * 256, r = idx >> 3, q = idx & 7;
        *(uint4*)&tile[r][q * 8] = *(const uint4*)&src[(size_t)(m0 + r) * 64 + q * 8];
    }
    __syncthreads();
    #pragma unroll
    for (int i = 0; i < 2; i++) {
        int idx = t + i * 256, d = idx >> 3, q = idx & 7;
        alignas(16) u16 tmp[8];
        #pragma unroll
        for (int j = 0; j < 8; j++) tmp[j] = tile[q * 8 + j][d];
        *(uint4*)&dst[(size_t)d * 1024 + m0 + q * 8] = *(uint4*)tmp;
    }
}

// ---------------- fused 4-layer residual flash attention ----------------
// grid: (NX/64, B*H). block 256 (4 waves, 16 q-rows each).
__global__ __launch_bounds__(256) void attn_kernel(const u16* __restrict__ qkv,
                                                   const int* __restrict__ x_mask,
                                                   const int* __restrict__ y_mask,
                                                   const u16* __restrict__ vt,
                                                   u16* __restrict__ obuf)
{
    __shared__ u16 Ks[4][64][72];
    __shared__ u16 Vs[64][72];
    __shared__ u16 Ps[4][16][72];
    __shared__ int yms[64];

    const int t = threadIdx.x;
    const int wid = t >> 6, lane = t & 63;
    const int lrow = lane & 15, kg = lane >> 4;
    const int bh = blockIdx.y, b = bh >> 3, h = bh & 7;
    const int n0 = blockIdx.x * 64;
    const int wrow0 = n0 + wid * 16;

    const size_t headoff = (size_t)b * 524288 + (size_t)h * 65536;
    const u16* VT = vt + (size_t)bh * 65536;

    // hoist Q fragments for all 4 layers
    bf16x8 aq[4][2];
    #pragma unroll
    for (int l = 0; l < 4; l++) {
        const u16* Q = qkv + (size_t)l * 2097152 + headoff;
        #pragma unroll
        for (int kk = 0; kk < 2; kk++)
            aq[l][kk] = *(const bf16x8*)&Q[(size_t)(wrow0 + lrow) * 64 + kk * 32 + kg * 8];
    }

    int xm[4];
    #pragma unroll
    for (int r = 0; r < 4; r++) xm[r] = x_mask[b * 1024 + wrow0 + kg * 4 + r];

    float mx[4][4], sm[4][4];
    f32x4 oacc[4][4];
    #pragma unroll
    for (int l = 0; l < 4; l++)
        #pragma unroll
        for (int r = 0; r < 4; r++) { mx[l][r] = -3e38f; sm[l][r] = 0.f; }
    #pragma unroll
    for (int l = 0; l < 4; l++)
        #pragma unroll
        for (int d = 0; d < 4; d++) oacc[l][d] = f32x4{0.f, 0.f, 0.f, 0.f};

    for (int mt = 0; mt < 16; mt++) {
        const int m0 = mt * 64;
        if (t < 64) yms[t] = y_mask[b * 1024 + m0 + t];
        #pragma unroll
        for (int l = 0; l < 4; l++) {
            const u16* Kl = qkv + (size_t)(4 + l) * 2097152 + headoff;
            #pragma unroll
            for (int i = 0; i < 2; i++) {
                int idx = t + i * 256, r = idx >> 3, q = idx & 7;
                *(uint4*)&Ks[l][r][q * 8] = *(const uint4*)&Kl[(size_t)(m0 + r) * 64 + q * 8];
            }
        }
        #pragma unroll
        for (int i = 0; i < 2; i++) {
            int idx = t + i * 256, r = idx >> 3, q = idx & 7;
            *(uint4*)&Vs[r][q * 8] = *(const uint4*)&VT[(size_t)r * 1024 + m0 + q * 8];
        }
        __syncthreads();

        #pragma unroll
        for (int l = 0; l < 4; l++) {
            // scores S = Q_l K_l^T for this wave's 16 rows x 64 cols
            f32x4 s[4];
            #pragma unroll
            for (int mf = 0; mf < 4; mf++) {
                f32x4 z = f32x4{0.f, 0.f, 0.f, 0.f};
                #pragma unroll
                for (int kk = 0; kk < 2; kk++) {
                    bf16x8 kb = *(const bf16x8*)&Ks[l][mf * 16 + lrow][kk * 32 + kg * 8];
                    z = __builtin_amdgcn_mfma_f32_16x16x32_bf16(aq[l][kk], kb, z, 0, 0, 0);
                }
                s[mf] = z;
            }
            // mask + scale + row max
            float rowmax[4];
            #pragma unroll
            for (int r = 0; r < 4; r++) rowmax[r] = -3e38f;
            #pragma unroll
            for (int mf = 0; mf < 4; mf++) {
                int ym = yms[mf * 16 + lrow];
                #pragma unroll
                for (int r = 0; r < 4; r++) {
                    float v = (xm[r] != 0 && ym != 0) ? s[mf][r] * 0.125f : -1e9f;
                    s[mf][r] = v;
                    rowmax[r] = fmaxf(rowmax[r], v);
                }
            }
            #pragma unroll
            for (int off = 1; off < 16; off <<= 1)
                #pragma unroll
                for (int r = 0; r < 4; r++)
                    rowmax[r] = fmaxf(rowmax[r], __shfl_xor(rowmax[r], off, 16));
            // online softmax update
            float fac[4], rs[4];
            #pragma unroll
            for (int r = 0; r < 4; r++) {
                float mn = fmaxf(mx[l][r], rowmax[r]);
                fac[r] = __expf(mx[l][r] - mn);
                mx[l][r] = mn;
                rs[r] = 0.f;
            }
            #pragma unroll
            for (int mf = 0; mf < 4; mf++)
                #pragma unroll
                for (int r = 0; r < 4; r++) {
                    float p = __expf(s[mf][r] - mx[l][r]);
                    s[mf][r] = p;
                    rs[r] += p;
                }
            #pragma unroll
            for (int off = 1; off < 16; off <<= 1)
                #pragma unroll
                for (int r = 0; r < 4; r++) rs[r] += __shfl_xor(rs[r], off, 16);
            #pragma unroll
            for (int r = 0; r < 4; r++) sm[l][r] = sm[l][r] * fac[r] + rs[r];
            #pragma unroll
            for (int d = 0; d < 4; d++)
                #pragma unroll
                for (int r = 0; r < 4; r++) oacc[l][d][r] *= fac[r];
            // write P (bf16) to per-wave LDS, reload as A-fragments
            #pragma unroll
            for (int mf = 0; mf < 4; mf++)
                #pragma unroll
                for (int r = 0; r < 4; r++)
                    Ps[wid][kg * 4 + r][mf * 16 + lrow] = f2bf(s[mf][r]);
            bf16x8 pa[2];
            #pragma unroll
            for (int kk = 0; kk < 2; kk++)
                pa[kk] = *(const bf16x8*)&Ps[wid][lrow][kk * 32 + kg * 8];
            #pragma unroll
            for (int d = 0; d < 4; d++) {
                #pragma unroll
                for (int kk = 0; kk < 2; kk++) {
                    bf16x8 vb = *(const bf16x8*)&Vs[d * 16 + lrow][kk * 32 + kg * 8];
                    oacc[l][d] = __builtin_amdgcn_mfma_f32_16x16x32_bf16(pa[kk], vb, oacc[l][d], 0, 0, 0);
                }
            }
        }
        __syncthreads();
    }

    // finalize: O = sum_l O_l / sum_l ; write merged-head bf16
    float inv[4][4];
    #pragma unroll
    for (int l = 0; l < 4; l++)
        #pragma unroll
        for (int r = 0; r < 4; r++) inv[l][r] = 1.f / sm[l][r];
    #pragma unroll
    for (int d = 0; d < 4; d++)
        #pragma unroll
        for (int r = 0; r < 4; r++) {
            float v = oacc[0][d][r] * inv[0][r] + oacc[1][d][r] * inv[1][r]
                    + oacc[2][d][r] * inv[2][r] + oacc[3][d][r] * inv[3][r];
            int row = wrow0 + kg * 4 + r;
            int col = h * 64 + d * 16 + lrow;
            obuf[(size_t)(b * 1024 + row) * 512 + col] = f2bf(v);
        }
}

// ---------------- LayerNorm (one wave per row of 512). MODE 0: write f32 + bf16; MODE 1: f32 only ----------------
template<int MODE>
__global__ __launch_bounds__(256) void ln_kernel(const float* __restrict__ in,
                                                 const float* __restrict__ g,
                                                 const float* __restrict__ be,
                                                 float* __restrict__ out32,
                                                 u16* __restrict__ out16)
{
    const int wid = threadIdx.x >> 6, lane = threadIdx.x & 63;
    const int row = blockIdx.x * 4 + wid;
    const float* x = in + (size_t)row * 512;
    float4 v1 = *(const float4*)&x[lane * 8];
    float4 v2 = *(const float4*)&x[lane * 8 + 4];
    float xv[8] = { v1.x, v1.y, v1.z, v1.w, v2.x, v2.y, v2.z, v2.w };
    float s = 0.f, s2 = 0.f;
    #pragma unroll
    for (int j = 0; j < 8; j++) { s += xv[j]; s2 += xv[j] * xv[j]; }
    #pragma unroll
    for (int off = 32; off > 0; off >>= 1) {
        s  += __shfl_xor(s, off, 64);
        s2 += __shfl_xor(s2, off, 64);
    }
    const float mean = s * (1.f / 512.f);
    const float var  = s2 * (1.f / 512.f) - mean * mean;
    const float rstd = rsqrtf(var + 1e-5f);
    float ov[8];
    #pragma unroll
    for (int j = 0; j < 8; j++) {
        int col = lane * 8 + j;
        ov[j] = (xv[j] - mean) * rstd * g[col] + be[col];
    }
    *(float4*)&out32[(size_t)row * 512 + lane * 8]     = float4{ ov[0], ov[1], ov[2], ov[3] };
    *(float4*)&out32[(size_t)row * 512 + lane * 8 + 4] = float4{ ov[4], ov[5], ov[6], ov[7] };
    if constexpr (MODE == 0) {
        alignas(16) u16 tmp[8];
        #pragma unroll
        for (int j = 0; j < 8; j++) tmp[j] = f2bf(ov[j]);
        *(uint4*)&out16[(size_t)row * 512 + lane * 8] = *(uint4*)tmp;
    }
}

extern "C" void kernel_launch(void* const* d_in, const int* in_sizes, int n_in,
                              void* d_out, int out_size, void* d_ws, size_t ws_size,
                              hipStream_t stream) {
    const float* x      = (const float*)d_in[0];
    const float* y      = (const float*)d_in[1];
    const int*   x_mask = (const int*)d_in[2];
    const int*   y_mask = (const int*)d_in[3];
    const float* Wq  = (const float*)d_in[4];
    const float* bq  = (const float*)d_in[5];
    const float* Wk  = (const float*)d_in[6];
    const float* bk  = (const float*)d_in[7];
    const float* Wv  = (const float*)d_in[8];
    const float* bv  = (const float*)d_in[9];
    const float* Wo  = (const float*)d_in[10];
    const float* bo  = (const float*)d_in[11];
    const float* g1  = (const float*)d_in[12];
    const float* be1 = (const float*)d_in[13];
    const float* g2  = (const float*)d_in[14];
    const float* be2 = (const float*)d_in[15];
    const float* W1  = (const float*)d_in[16];
    const float* bf1 = (const float*)d_in[17];
    const float* W2  = (const float*)d_in[18];
    const float* bf2 = (const float*)d_in[19];

    char* p = (char*)d_ws;
    auto alloc = [&](size_t bytes) { char* r = p; p += (bytes + 255) & ~(size_t)255; return r; };
    u16*   x16   = (u16*)alloc(2097152ULL * 2);
    u16*   y16   = (u16*)alloc(2097152ULL * 2);
    u16*   wt    = (u16*)alloc(4718592ULL * 2);
    u16*   qkv   = (u16*)alloc(9ULL * 2097152 * 2);
    u16*   vt    = (u16*)alloc(2097152ULL * 2);
    u16*   obuf  = (u16*)alloc(2097152ULL * 2);
    float* xo    = (float*)alloc(2097152ULL * 4);
    float* h32   = (float*)alloc(2097152ULL * 4);
    u16*   h16   = (u16*)alloc(2097152ULL * 2);
    u16*   ffmid = (u16*)alloc(8388608ULL * 2);
    float* ffout = (float*)alloc(2097152ULL * 4);
    if ((size_t)(p - (char*)d_ws) > ws_size) return;  // ws too small: bail cleanly

    // 1) convert activations to bf16
    cvt_kernel<<<2048, 256, 0, stream>>>(x, x16, 2097152);
    cvt_kernel<<<2048, 256, 0, stream>>>(y, y16, 2097152);
    // 2) transpose+convert the 12 needed weight matrices
    wtrans_kernel<<<dim3(64, 64, 12), dim3(32, 8), 0, stream>>>(Wq, Wk, Wv, Wo, W1, W2, wt);
    // 3) Q_l, K_l (l=0..3), V_3 projections
    qkv_gemm_kernel<<<dim3(4, 32, 9), 256, 0, stream>>>(x16, y16, wt, qkv, bq, bk, bv);
    // 4) per-head V transpose
    vtrans_kernel<<<dim3(16, 32), 256, 0, stream>>>(qkv + 8ULL * 2097152, vt);
    // 5) fused 4-layer residual attention
    attn_kernel<<<dim3(16, 32), 256, 0, stream>>>(qkv, x_mask, y_mask, vt, obuf);
    // 6) o@Wo + bo + x  -> xo (f32)
    gemm_bt_kernel<1><<<dim3(4, 32), 256, 0, stream>>>(obuf, wt + 2359296, bo + 3 * 512, xo, x, 512, 512);
    // 7) LN1 -> h (f32 + bf16)
    ln_kernel<0><<<1024, 256, 0, stream>>>(xo, g1 + 3 * 512, be1 + 3 * 512, h32, h16);
    // 8) gelu(h@W1 + bf1) -> ffmid (bf16)
    gemm_bt_kernel<2><<<dim3(16, 32), 256, 0, stream>>>(h16, wt + 2621440, bf1 + 3 * 2048, ffmid, nullptr, 2048, 512);
    // 9) ffmid@W2 + bf2 + h -> ffout (f32)
    gemm_bt_kernel<1><<<dim3(4, 32), 256, 0, stream>>>(ffmid, wt + 3670016, bf2 + 3 * 512, ffout, h32, 512, 2048);
    // 10) LN2 -> d_out (f32)
    ln_kernel<1><<<1024, 256, 0, stream>>>(ffout, g2 + 3 * 512, be2 + 3 * 512, (float*)d_out, nullptr);
}